// Round 7
// baseline (117.540 us; speedup 1.0000x reference)
//
#include <hip/hip_runtime.h>

#define F_IN 256
#define NHEAD 4
#define DOUT 64
#define FOUT 256   // NHEAD*DOUT
#define NEG_SLOPE 0.2f
#define BCAP 64    // bucket capacity per node (max degree ~40 for Poisson(16))
#define PREP_BLKS 16

typedef __attribute__((ext_vector_type(8))) short bf16x8;
typedef __attribute__((ext_vector_type(4))) float f32x4;

// fp32 -> bf16 round-to-nearest-even (no NaN inputs here)
__device__ __forceinline__ unsigned short f2bf(float x) {
    unsigned u = __float_as_uint(x);
    return (unsigned short)((u + 0x7FFFu + ((u >> 16) & 1u)) >> 16);
}
// bf16 pair unpack from packed u32 (little-endian: low short = even element)
__device__ __forceinline__ float bflo(unsigned u) { return __uint_as_float(u << 16); }
__device__ __forceinline__ float bfhi(unsigned u) { return __uint_as_float(u & 0xFFFF0000u); }

// ---------------------------------------------------------------------------
// Heterogeneous: blocks [0,16) transpose W -> Wt bf16 [N][K] via LDS tiles;
// blocks [16, ...) do bucketed CSR fill (rides free under fill's atomics).
// ---------------------------------------------------------------------------
__global__ __launch_bounds__(256) void k_prep_fill(
    const float* __restrict__ W, unsigned short* __restrict__ Wt,
    const int* __restrict__ src, const int* __restrict__ dst,
    const float* __restrict__ dist, int* __restrict__ cnt,
    int2* __restrict__ bkt, int E_)
{
    __shared__ float tile[64][65];
    if (blockIdx.x < PREP_BLKS) {
        int bi = blockIdx.x >> 2, bj = blockIdx.x & 3;  // k-tile, n-tile
        int t = threadIdx.x;
        int r0 = t >> 6, c = t & 63;
#pragma unroll
        for (int it = 0; it < 16; ++it) {
            int r = it * 4 + r0;
            tile[r][c] = W[(size_t)(bi * 64 + r) * FOUT + bj * 64 + c];
        }
        __syncthreads();
#pragma unroll
        for (int it = 0; it < 16; ++it) {
            int r = it * 4 + r0;   // r: n-local, c: k-local
            Wt[(size_t)(bj * 64 + r) * F_IN + bi * 64 + c] = f2bf(tile[c][r]);
        }
        return;
    }
    int e = (blockIdx.x - PREP_BLKS) * 256 + threadIdx.x;
    if (e >= E_) return;
    int d = dst[e];
    int p = atomicAdd(&cnt[d], 1);
    if (p < BCAP) bkt[(size_t)d * BCAP + p] = make_int2(src[e], __float_as_int(dist[e]));
}

// ---------------------------------------------------------------------------
// ft = feat @ W via bf16 MFMA (fp32 accum). Block = 4 waves, BM=64 x BN=256;
// wave w owns head w. ft stored HEAD-SLICED: ftb4[h][n][64] so k_agg's
// per-head working set is a contiguous 4.1 MB slice (per-XCD-L2-resident).
// MFMA 16x16x32 layout (m89-verified): A row=l&15,k=(l>>4)*8+e;
// B col=l&15,k=(l>>4)*8+e; D col=l&15,row=(l>>4)*4+r.
// ---------------------------------------------------------------------------
__global__ __launch_bounds__(256) void k_gemm(
    const float* __restrict__ feat, const unsigned short* __restrict__ Wt,
    const float* __restrict__ wsrc, const float* __restrict__ wdst,
    unsigned short* __restrict__ ftb4, float* __restrict__ esrc,
    float* __restrict__ edst, int n)
{
    __shared__ unsigned short A_lds[64 * 40];
    const int m0   = blockIdx.x * 64;
    const int tid  = threadIdx.x;
    const int w    = tid >> 6;          // wave id == head id
    const int lane = tid & 63;
    const int l15  = lane & 15, l4 = lane >> 4;

    const int srow = tid >> 2, skg = tid & 3;   // staging: 64 rows x 4 k-groups
    const float* gA = &feat[(size_t)(m0 + srow) * F_IN + skg * 8];
    unsigned short* sA = &A_lds[srow * 40 + skg * 8];

    f32x4 acc[4][4];
#pragma unroll
    for (int mi = 0; mi < 4; ++mi)
#pragma unroll
        for (int ni = 0; ni < 4; ++ni)
            acc[mi][ni] = (f32x4){0.f, 0.f, 0.f, 0.f};

    for (int ks = 0; ks < F_IN / 32; ++ks) {
        float4 a0 = *(const float4*)(gA + ks * 32);
        float4 a1 = *(const float4*)(gA + ks * 32 + 4);
        if (ks) __syncthreads();            // previous tile fully consumed
        bf16x8 pk;
        pk[0] = (short)f2bf(a0.x); pk[1] = (short)f2bf(a0.y);
        pk[2] = (short)f2bf(a0.z); pk[3] = (short)f2bf(a0.w);
        pk[4] = (short)f2bf(a1.x); pk[5] = (short)f2bf(a1.y);
        pk[6] = (short)f2bf(a1.z); pk[7] = (short)f2bf(a1.w);
        *(bf16x8*)sA = pk;
        __syncthreads();

        bf16x8 bfr[4];
#pragma unroll
        for (int ni = 0; ni < 4; ++ni)
            bfr[ni] = *(const bf16x8*)&Wt[(size_t)(w * 64 + ni * 16 + l15) * F_IN + ks * 32 + l4 * 8];
        bf16x8 afr[4];
#pragma unroll
        for (int mi = 0; mi < 4; ++mi)
            afr[mi] = *(const bf16x8*)&A_lds[(mi * 16 + l15) * 40 + l4 * 8];
#pragma unroll
        for (int mi = 0; mi < 4; ++mi)
#pragma unroll
            for (int ni = 0; ni < 4; ++ni)
                acc[mi][ni] = __builtin_amdgcn_mfma_f32_16x16x32_bf16(
                    afr[mi], bfr[ni], acc[mi][ni], 0, 0, 0);
    }

    unsigned short* ftb_h = ftb4 + (size_t)w * ((size_t)n * DOUT);
    float wsv[4], wdv[4];
#pragma unroll
    for (int ni = 0; ni < 4; ++ni) {
        wsv[ni] = wsrc[w * 64 + ni * 16 + l15];
        wdv[ni] = wdst[w * 64 + ni * 16 + l15];
    }
#pragma unroll
    for (int mi = 0; mi < 4; ++mi) {
#pragma unroll
        for (int r = 0; r < 4; ++r) {
            int row = m0 + mi * 16 + l4 * 4 + r;
            float ps = 0.f, pd = 0.f;
#pragma unroll
            for (int ni = 0; ni < 4; ++ni) {
                float v = acc[mi][ni][r];
                ftb_h[(size_t)row * DOUT + ni * 16 + l15] = f2bf(v);
                ps += v * wsv[ni];
                pd += v * wdv[ni];
            }
#pragma unroll
            for (int m = 1; m < 16; m <<= 1) {
                ps += __shfl_xor(ps, m);
                pd += __shfl_xor(pd, m);
            }
            if (l15 == 0) {
                esrc[row * NHEAD + w] = ps;
                edst[row * NHEAD + w] = pd;
            }
        }
    }
}

// ---------------------------------------------------------------------------
// Fused node-centric softmax + aggregation, XCD-head-locked.
// head = blockIdx & 3; with round-robin XCD assignment (xcd = blockIdx % 8)
// every XCD touches exactly ONE head's 4.1 MB ftb4 slice -> L2-resident.
// One wave per (node, head): 8 edge-groups x 8 col-lanes (16 B each);
// group-reduce via shfl_xor{8,16,32}. No max pass (logits bounded by
// construction, softmax shift-invariant, exp stays in fp32 range).
// ---------------------------------------------------------------------------
__global__ __launch_bounds__(256) void k_agg(
    const int* __restrict__ cnt, const int2* __restrict__ bkt,
    const float* __restrict__ esrc, const float* __restrict__ edst,
    const unsigned short* __restrict__ ftb4, float* __restrict__ out, int n)
{
    int b = blockIdx.x;
    int head = b & 3;                       // == (b % 8) & 3: XCD-locked head
    int node = (b >> 2) * 4 + (threadIdx.x >> 6);
    if (node >= n) return;
    int lane = threadIdx.x & 63;
    int g = lane >> 3, j = lane & 7;        // edge-group, col-group
    int cn = cnt[node]; if (cn > BCAP) cn = BCAP;
    const int2* bk = &bkt[(size_t)node * BCAP];
    const unsigned short* slice = ftb4 + (size_t)head * ((size_t)n * DOUT);
    float ed = edst[node * NHEAD + head];

    float denom = 0.f;
    float acc[8] = {0,0,0,0,0,0,0,0};

    for (int i = 0; i < cn; i += 8) {
        int idx = i + g;
        bool valid = idx < cn;
        int2 c = valid ? bk[idx] : make_int2(0, 0);   // row 0: safe dummy
        float lg = esrc[c.x * NHEAD + head] + ed;
        lg = (lg >= 0.f) ? lg : NEG_SLOPE * lg;
        float p = valid ? __expf(lg) : 0.f;
        float a = p * __int_as_float(c.y);
        denom += p;
        int4 r = *(const int4*)&slice[(size_t)c.x * DOUT + j * 8];
        acc[0] += bflo(r.x) * a; acc[1] += bfhi(r.x) * a;
        acc[2] += bflo(r.y) * a; acc[3] += bfhi(r.y) * a;
        acc[4] += bflo(r.z) * a; acc[5] += bfhi(r.z) * a;
        acc[6] += bflo(r.w) * a; acc[7] += bfhi(r.w) * a;
    }

    // reduce across the 8 edge-groups (lane bits 3..5); denom becomes exact
    // (each group's partial counted once), acc completes per column.
#pragma unroll
    for (int m = 8; m < 64; m <<= 1) {
        denom += __shfl_xor(denom, m);
#pragma unroll
        for (int k = 0; k < 8; ++k) acc[k] += __shfl_xor(acc[k], m);
    }

    float inv = (denom > 0.f) ? 1.f / denom : 0.f;
    if (g == 0) {
        float4 o0 = { acc[0] * inv, acc[1] * inv, acc[2] * inv, acc[3] * inv };
        float4 o1 = { acc[4] * inv, acc[5] * inv, acc[6] * inv, acc[7] * inv };
        size_t o = (size_t)node * FOUT + head * DOUT + j * 8;
        *(float4*)&out[o]     = o0;
        *(float4*)&out[o + 4] = o1;
    }
}

// ---------------------------------------------------------------------------
extern "C" void kernel_launch(void* const* d_in, const int* in_sizes, int n_in,
                              void* d_out, int out_size, void* d_ws, size_t ws_size,
                              hipStream_t stream)
{
    const float* feat = (const float*)d_in[0];
    const float* dist = (const float*)d_in[1];
    const float* W    = (const float*)d_in[2];
    const float* wsrc = (const float*)d_in[3];
    const float* wdst = (const float*)d_in[4];
    const int*   src  = (const int*)d_in[5];
    const int*   dst  = (const int*)d_in[6];
    float* out = (float*)d_out;

    const int n  = in_sizes[0] / F_IN;   // 32000
    const int E_ = in_sizes[5];          // 512000

    // workspace layout (4-byte units; every block 16B-aligned by construction)
    float* ws = (float*)d_ws;
    size_t off = 0;
    unsigned short* ftb4 = (unsigned short*)(ws + off); off += (size_t)n * FOUT / 2;   // 16.4 MB
    unsigned short* Wt   = (unsigned short*)(ws + off); off += (size_t)F_IN * FOUT / 2; // 128 KB
    float* esrc = ws + off; off += (size_t)n * NHEAD;             // 512 KB
    float* edst = ws + off; off += (size_t)n * NHEAD;             // 512 KB
    int2*  bkt  = (int2*)(ws + off); off += (size_t)n * BCAP * 2; // 16.4 MB
    int*   cnt  = (int*)(ws + off);  off += (size_t)n;            // zero-init

    hipMemsetAsync(cnt, 0, (size_t)n * sizeof(int), stream);

    int eb = (E_ + 255) / 256;
    k_prep_fill<<<PREP_BLKS + eb, 256, 0, stream>>>(W, Wt, src, dst, dist, cnt, bkt, E_);

    k_gemm<<<n / 64, 256, 0, stream>>>(feat, Wt, wsrc, wdst, ftb4, esrc, edst, n);

    k_agg<<<n, 256, 0, stream>>>(cnt, bkt, esrc, edst, ftb4, out, n);
}

// Round 8
// 84.380 us; speedup vs baseline: 1.3930x; 1.3930x over previous
//
#include <hip/hip_runtime.h>

#define F_IN 256
#define NHEAD 4
#define DOUT 64
#define FOUT 256   // NHEAD*DOUT
#define NEG_SLOPE 0.2f
#define BCAP 64    // bucket capacity per node (max degree ~40 for Poisson(16))
#define PREP_BLKS 16

typedef __attribute__((ext_vector_type(8))) short bf16x8;
typedef __attribute__((ext_vector_type(4))) float f32x4;

// fp32 -> bf16 round-to-nearest-even (no NaN inputs here)
__device__ __forceinline__ unsigned short f2bf(float x) {
    unsigned u = __float_as_uint(x);
    return (unsigned short)((u + 0x7FFFu + ((u >> 16) & 1u)) >> 16);
}
// bf16 pair unpack from packed u32 (little-endian: low short = even element)
__device__ __forceinline__ float bflo(unsigned u) { return __uint_as_float(u << 16); }
__device__ __forceinline__ float bfhi(unsigned u) { return __uint_as_float(u & 0xFFFF0000u); }

// ---------------------------------------------------------------------------
// Blocks [0,16): transpose W -> Wt bf16 [N][K] via LDS tiles.
// Blocks [16,48): zero cnt (int4 stores). Replaces the hipMemsetAsync node.
// ---------------------------------------------------------------------------
__global__ __launch_bounds__(256) void k_prep_zero(
    const float* __restrict__ W, unsigned short* __restrict__ Wt,
    int* __restrict__ cnt, int n)
{
    if (blockIdx.x < PREP_BLKS) {
        __shared__ float tile[64][65];
        int bi = blockIdx.x >> 2, bj = blockIdx.x & 3;  // k-tile, n-tile
        int t = threadIdx.x;
        int r0 = t >> 6, c = t & 63;
#pragma unroll
        for (int it = 0; it < 16; ++it) {
            int r = it * 4 + r0;
            tile[r][c] = W[(size_t)(bi * 64 + r) * FOUT + bj * 64 + c];
        }
        __syncthreads();
#pragma unroll
        for (int it = 0; it < 16; ++it) {
            int r = it * 4 + r0;   // r: n-local, c: k-local
            Wt[(size_t)(bj * 64 + r) * F_IN + bi * 64 + c] = f2bf(tile[c][r]);
        }
        return;
    }
    int i = (blockIdx.x - PREP_BLKS) * 256 + threadIdx.x;
    if (i < n / 4) ((int4*)cnt)[i] = make_int4(0, 0, 0, 0);
}

// ---------------------------------------------------------------------------
// Heterogeneous: blocks [0, GB) = MFMA GEMM tiles (start at t=0, long pole);
// blocks [GB, GB+FB) = bucketed CSR fill. Fill is atomic-latency-bound,
// GEMM is MFMA/LDS-bound -> complementary pipes, fill hides under GEMM.
//
// GEMM: ft = feat @ W, bf16 MFMA fp32-accum, BM=64 x BN=256, wave w = head w.
// A staged fp32->bf16 in LDS (stride 40: 2-way = free); B-frags from L2-hot
// Wt[n][k]. Epilogue: bf16 ft store (flat [n][FOUT] layout) + fused logits.
// MFMA 16x16x32 layout (m89-verified): A row=l&15,k=(l>>4)*8+e;
// B col=l&15,k=(l>>4)*8+e; D col=l&15,row=(l>>4)*4+r.
// ---------------------------------------------------------------------------
__global__ __launch_bounds__(256) void k_gemm_fill(
    const float* __restrict__ feat, const unsigned short* __restrict__ Wt,
    const float* __restrict__ wsrc, const float* __restrict__ wdst,
    unsigned short* __restrict__ ftb, float* __restrict__ esrc,
    float* __restrict__ edst,
    const int* __restrict__ src, const int* __restrict__ dst,
    const float* __restrict__ dist, int* __restrict__ cnt,
    int2* __restrict__ bkt, int E_, int GB)
{
    if (blockIdx.x >= GB) {
        int e = (blockIdx.x - GB) * 256 + threadIdx.x;
        if (e >= E_) return;
        int d = dst[e];
        int p = atomicAdd(&cnt[d], 1);
        if (p < BCAP) bkt[(size_t)d * BCAP + p] = make_int2(src[e], __float_as_int(dist[e]));
        return;
    }

    __shared__ unsigned short A_lds[64 * 40];
    const int m0   = blockIdx.x * 64;
    const int tid  = threadIdx.x;
    const int w    = tid >> 6;          // wave id == head id
    const int lane = tid & 63;
    const int l15  = lane & 15, l4 = lane >> 4;

    const int srow = tid >> 2, skg = tid & 3;   // staging: 64 rows x 4 k-groups
    const float* gA = &feat[(size_t)(m0 + srow) * F_IN + skg * 8];
    unsigned short* sA = &A_lds[srow * 40 + skg * 8];

    f32x4 acc[4][4];
#pragma unroll
    for (int mi = 0; mi < 4; ++mi)
#pragma unroll
        for (int ni = 0; ni < 4; ++ni)
            acc[mi][ni] = (f32x4){0.f, 0.f, 0.f, 0.f};

    for (int ks = 0; ks < F_IN / 32; ++ks) {
        float4 a0 = *(const float4*)(gA + ks * 32);
        float4 a1 = *(const float4*)(gA + ks * 32 + 4);
        if (ks) __syncthreads();            // previous tile fully consumed
        bf16x8 pk;
        pk[0] = (short)f2bf(a0.x); pk[1] = (short)f2bf(a0.y);
        pk[2] = (short)f2bf(a0.z); pk[3] = (short)f2bf(a0.w);
        pk[4] = (short)f2bf(a1.x); pk[5] = (short)f2bf(a1.y);
        pk[6] = (short)f2bf(a1.z); pk[7] = (short)f2bf(a1.w);
        *(bf16x8*)sA = pk;
        __syncthreads();

        bf16x8 bfr[4];
#pragma unroll
        for (int ni = 0; ni < 4; ++ni)
            bfr[ni] = *(const bf16x8*)&Wt[(size_t)(w * 64 + ni * 16 + l15) * F_IN + ks * 32 + l4 * 8];
        bf16x8 afr[4];
#pragma unroll
        for (int mi = 0; mi < 4; ++mi)
            afr[mi] = *(const bf16x8*)&A_lds[(mi * 16 + l15) * 40 + l4 * 8];
#pragma unroll
        for (int mi = 0; mi < 4; ++mi)
#pragma unroll
            for (int ni = 0; ni < 4; ++ni)
                acc[mi][ni] = __builtin_amdgcn_mfma_f32_16x16x32_bf16(
                    afr[mi], bfr[ni], acc[mi][ni], 0, 0, 0);
    }

    float wsv[4], wdv[4];
#pragma unroll
    for (int ni = 0; ni < 4; ++ni) {
        wsv[ni] = wsrc[w * 64 + ni * 16 + l15];
        wdv[ni] = wdst[w * 64 + ni * 16 + l15];
    }
#pragma unroll
    for (int mi = 0; mi < 4; ++mi) {
#pragma unroll
        for (int r = 0; r < 4; ++r) {
            int row = m0 + mi * 16 + l4 * 4 + r;
            float ps = 0.f, pd = 0.f;
#pragma unroll
            for (int ni = 0; ni < 4; ++ni) {
                float v = acc[mi][ni][r];
                ftb[(size_t)row * FOUT + w * 64 + ni * 16 + l15] = f2bf(v);
                ps += v * wsv[ni];
                pd += v * wdv[ni];
            }
#pragma unroll
            for (int m = 1; m < 16; m <<= 1) {
                ps += __shfl_xor(ps, m);
                pd += __shfl_xor(pd, m);
            }
            if (l15 == 0) {
                esrc[row * NHEAD + w] = ps;
                edst[row * NHEAD + w] = pd;
            }
        }
    }
}

// ---------------------------------------------------------------------------
// Fused node-centric softmax + aggregation (round-6 proven version).
// One wave per node; each gather instruction fetches TWO edges' ft rows
// (lanes 0-31 edge i @16B/lane, lanes 32-63 edge i+1), unrolled x2 (4 edges
// per iter, 2 independent chains). Cross-half combine via shfl_xor(.,32).
// No max pass (logits bounded by construction, softmax shift-invariant).
// ---------------------------------------------------------------------------
__global__ __launch_bounds__(256) void k_agg(
    const int* __restrict__ cnt, const int2* __restrict__ bkt,
    const float* __restrict__ esrc, const float* __restrict__ edst,
    const unsigned short* __restrict__ ftb, float* __restrict__ out, int n)
{
    int node = blockIdx.x * 4 + (threadIdx.x >> 6);
    if (node >= n) return;
    int lane = threadIdx.x & 63;
    int half = lane >> 5;            // which edge of a pair
    int col  = (lane & 31) * 8;      // 8 output columns per lane
    int h    = (lane & 31) >> 3;     // head = col/64
    int cn = cnt[node]; if (cn > BCAP) cn = BCAP;
    const int2* b = &bkt[(size_t)node * BCAP];
    float ed = edst[node * NHEAD + h];

    float denom = 0.f;
    float acc[8] = {0,0,0,0,0,0,0,0};

    for (int i = 0; i < cn; i += 4) {
        int jA = i + half, jB = i + 2 + half;
        bool vA = jA < cn, vB = jB < cn;
        int2 cA = make_int2(0, 0), cB = make_int2(0, 0);   // row 0: safe dummy
        if (vA) cA = b[jA];
        if (vB) cB = b[jB];

        float lgA = esrc[cA.x * NHEAD + h] + ed;
        float lgB = esrc[cB.x * NHEAD + h] + ed;
        lgA = (lgA >= 0.f) ? lgA : NEG_SLOPE * lgA;
        lgB = (lgB >= 0.f) ? lgB : NEG_SLOPE * lgB;
        float pA = vA ? __expf(lgA) : 0.f;
        float pB = vB ? __expf(lgB) : 0.f;

        int4 rA = *(const int4*)&ftb[(size_t)cA.x * FOUT + col];
        int4 rB = *(const int4*)&ftb[(size_t)cB.x * FOUT + col];

        float aA = pA * __int_as_float(cA.y);   // cA.y==0 when invalid
        float aB = pB * __int_as_float(cB.y);
        denom += pA + pB;

        acc[0] += bflo(rA.x) * aA + bflo(rB.x) * aB;
        acc[1] += bfhi(rA.x) * aA + bfhi(rB.x) * aB;
        acc[2] += bflo(rA.y) * aA + bflo(rB.y) * aB;
        acc[3] += bfhi(rA.y) * aA + bfhi(rB.y) * aB;
        acc[4] += bflo(rA.z) * aA + bflo(rB.z) * aB;
        acc[5] += bfhi(rA.z) * aA + bfhi(rB.z) * aB;
        acc[6] += bflo(rA.w) * aA + bflo(rB.w) * aB;
        acc[7] += bfhi(rA.w) * aA + bfhi(rB.w) * aB;
    }

    // combine the two half-wave partials
    denom += __shfl_xor(denom, 32);
#pragma unroll
    for (int k = 0; k < 8; ++k) acc[k] += __shfl_xor(acc[k], 32);

    float inv = (denom > 0.f) ? 1.f / denom : 0.f;
    if (half == 0) {
        float4 o0 = { acc[0] * inv, acc[1] * inv, acc[2] * inv, acc[3] * inv };
        float4 o1 = { acc[4] * inv, acc[5] * inv, acc[6] * inv, acc[7] * inv };
        *(float4*)&out[(size_t)node * FOUT + col]     = o0;
        *(float4*)&out[(size_t)node * FOUT + col + 4] = o1;
    }
}

// ---------------------------------------------------------------------------
extern "C" void kernel_launch(void* const* d_in, const int* in_sizes, int n_in,
                              void* d_out, int out_size, void* d_ws, size_t ws_size,
                              hipStream_t stream)
{
    const float* feat = (const float*)d_in[0];
    const float* dist = (const float*)d_in[1];
    const float* W    = (const float*)d_in[2];
    const float* wsrc = (const float*)d_in[3];
    const float* wdst = (const float*)d_in[4];
    const int*   src  = (const int*)d_in[5];
    const int*   dst  = (const int*)d_in[6];
    float* out = (float*)d_out;

    const int n  = in_sizes[0] / F_IN;   // 32000
    const int E_ = in_sizes[5];          // 512000

    // workspace layout (4-byte units; every block 16B-aligned by construction)
    float* ws = (float*)d_ws;
    size_t off = 0;
    unsigned short* ftb = (unsigned short*)(ws + off); off += (size_t)n * FOUT / 2;    // 16.4 MB
    unsigned short* Wt  = (unsigned short*)(ws + off); off += (size_t)F_IN * FOUT / 2; // 128 KB
    float* esrc = ws + off; off += (size_t)n * NHEAD;             // 512 KB
    float* edst = ws + off; off += (size_t)n * NHEAD;             // 512 KB
    int2*  bkt  = (int2*)(ws + off); off += (size_t)n * BCAP * 2; // 16.4 MB
    int*   cnt  = (int*)(ws + off);  off += (size_t)n;

    const int ZB = (n / 4 + 255) / 256;                // 32 zero blocks
    k_prep_zero<<<PREP_BLKS + ZB, 256, 0, stream>>>(W, Wt, cnt, n);

    const int GB = n / 64;                             // 500 gemm blocks
    const int FB = (E_ + 255) / 256;                   // 2000 fill blocks
    k_gemm_fill<<<GB + FB, 256, 0, stream>>>(feat, Wt, wsrc, wdst, ftb, esrc, edst,
                                             src, dst, dist, cnt, bkt, E_, GB);

    k_agg<<<(n + 3) / 4, 256, 0, stream>>>(cnt, bkt, esrc, edst, ftb, out, n);
}